// Round 15
// baseline (313.708 us; speedup 1.0000x reference)
//
#include <hip/hip_runtime.h>

#define NN 4096
#define DD 512
#define HH 8
#define FF 64
#define LRELU_ALPHA 0.2f
#define SP 72   // LDS row stride in bf16 elems

typedef __attribute__((ext_vector_type(8))) short bf16x8;
typedef __attribute__((ext_vector_type(4))) float f32x4;

__device__ __forceinline__ float f4c(const float4& v, int k) {
    return k == 0 ? v.x : (k == 1 ? v.y : (k == 2 ? v.z : v.w));
}
__device__ __forceinline__ void f4s(float4& v, int k, float x) {
    if (k == 0) v.x = x; else if (k == 1) v.y = x; else if (k == 2) v.z = x; else v.w = x;
}
__device__ __forceinline__ unsigned short f2bf(float x) {   // RNE float->bf16
    unsigned u = __float_as_uint(x);
    return (unsigned short)((u + 0x7fffu + ((u >> 16) & 1u)) >> 16);
}
__device__ __forceinline__ float bf2f(unsigned short h) {
    return __uint_as_float(((unsigned)h) << 16);
}
// monotone float<->uint key for atomicMax on arbitrary-sign floats
__device__ __forceinline__ unsigned fkey(float x) {
    unsigned u = __float_as_uint(x);
    return (u & 0x80000000u) ? ~u : (u | 0x80000000u);
}
__device__ __forceinline__ float funkey(unsigned k) {
    unsigned u = (k & 0x80000000u) ? (k ^ 0x80000000u) : ~k;
    return __uint_as_float(u);
}
// CK-style barrier: drain LDS counts only; in-flight global->register loads survive.
__device__ __forceinline__ void sync_lds() {
    asm volatile("s_waitcnt lgkmcnt(0)\n\ts_barrier" ::: "memory");
}

// ================= Kernel 1: fused prep =================
__global__ __launch_bounds__(256) void k_prep(const int* __restrict__ adj,
                                              const float* __restrict__ W,
                                              unsigned* __restrict__ adjw,
                                              unsigned short* __restrict__ wt_hi,
                                              unsigned short* __restrict__ wt_lo,
                                              unsigned* __restrict__ mxkey,
                                              float* __restrict__ hpsum) {
    __shared__ float tile[64][65];
    int b = blockIdx.x, t = threadIdx.x;
    if (b < 4096) {
        int lane = t & 63;
        #pragma unroll
        for (int i = 0; i < 16; i++) {
            int tid = ((b * 16 + i) << 8) + t;
            unsigned long long mask = __ballot(adj[tid] > 0);
            if (lane == 0) {
                int base = tid >> 5;
                adjw[base] = (unsigned)mask;
                adjw[base + 1] = (unsigned)(mask >> 32);
            }
        }
    } else if (b < 4160) {
        int idx = b - 4096;
        int h = idx >> 3;
        int d0 = (idx & 7) * 64;
        #pragma unroll
        for (int kidx = 0; kidx < 4; kidx++) {
            int id = t + 256 * kidx;
            int dd = id >> 4, f4i = (id & 15) * 4;
            float4 v = *(const float4*)(W + ((size_t)(h * DD + d0 + dd)) * FF + f4i);
            tile[dd][f4i] = v.x; tile[dd][f4i + 1] = v.y;
            tile[dd][f4i + 2] = v.z; tile[dd][f4i + 3] = v.w;
        }
        __syncthreads();
        int f = t >> 2, c = (t & 3) * 16;
        union { unsigned short s[16]; uint4 v[2]; } hb, lb;
        #pragma unroll
        for (int q = 0; q < 16; q++) {
            float v = tile[c + q][f];
            unsigned short hi = f2bf(v);
            hb.s[q] = hi;
            lb.s[q] = f2bf(v - bf2f(hi));
        }
        uint4* dh = (uint4*)(wt_hi + ((size_t)h * FF + f) * DD + d0 + c);
        uint4* dl = (uint4*)(wt_lo + ((size_t)h * FF + f) * DD + d0 + c);
        dh[0] = hb.v[0]; dh[1] = hb.v[1];
        dl[0] = lb.v[0]; dl[1] = lb.v[1];
    } else {
        if (t < 16) mxkey[t] = 0u;
        hpsum[t] = 0.f;
        hpsum[t + 256] = 0.f;
    }
}

// ================= Kernel 2: hp GEMM, 3-stage pipelined K-loop ========
__global__ __launch_bounds__(256) void k_hp_mfma(const float* __restrict__ hmat,
                                                 const unsigned short* __restrict__ whi,
                                                 const unsigned short* __restrict__ wlo,
                                                 const float* __restrict__ a,
                                                 unsigned short* __restrict__ hpT_hi,
                                                 float* __restrict__ fs,
                                                 float* __restrict__ fd,
                                                 float* __restrict__ hpsum,
                                                 unsigned* __restrict__ mxkey) {
    __shared__ char smem[4 * 64 * SP * 2];   // 36864 B
    unsigned short* ah = (unsigned short*)smem;
    unsigned short* al = ah + 64 * SP;
    unsigned short* bh = al + 64 * SP;
    unsigned short* bl = bh + 64 * SP;

    int t = threadIdx.x;
    int h = blockIdx.y;
    int n0 = blockIdx.x * 64;
    int lane = t & 63;
    int w = t >> 6;
    int R0 = (w >> 1) * 32, F0 = (w & 1) * 32;
    int am = lane & 15, aq = lane >> 4;
    int sr = t >> 2, sc = (t & 3) * 16;

    const float* gha = hmat + (size_t)(n0 + sr) * DD;
    const unsigned short* gbh = whi + ((size_t)h * FF + sr) * DD;
    const unsigned short* gbl = wlo + ((size_t)h * FF + sr) * DD;

    float4 p0, p1, p2, p3;
    uint4 w0, w1, x0, x1;
    auto gload = [&](int kk) {
        p0 = *(const float4*)(gha + kk + sc);
        p1 = *(const float4*)(gha + kk + sc + 4);
        p2 = *(const float4*)(gha + kk + sc + 8);
        p3 = *(const float4*)(gha + kk + sc + 12);
        const uint4* s2 = (const uint4*)(gbh + kk + sc);
        const uint4* s3 = (const uint4*)(gbl + kk + sc);
        w0 = s2[0]; w1 = s2[1]; x0 = s3[0]; x1 = s3[1];
    };
    auto wstage = [&]() {
        union { unsigned short s[16]; uint4 v[2]; } hb, lb;
        #pragma unroll
        for (int q = 0; q < 16; q++) {
            float v = q < 4 ? f4c(p0, q) : q < 8 ? f4c(p1, q - 4)
                      : q < 12 ? f4c(p2, q - 8) : f4c(p3, q - 12);
            unsigned short hi = f2bf(v);
            hb.s[q] = hi;
            lb.s[q] = f2bf(v - bf2f(hi));
        }
        *(uint4*)(ah + sr * SP + sc) = hb.v[0]; *(uint4*)(ah + sr * SP + sc + 8) = hb.v[1];
        *(uint4*)(al + sr * SP + sc) = lb.v[0]; *(uint4*)(al + sr * SP + sc + 8) = lb.v[1];
        *(uint4*)(bh + sr * SP + sc) = w0; *(uint4*)(bh + sr * SP + sc + 8) = w1;
        *(uint4*)(bl + sr * SP + sc) = x0; *(uint4*)(bl + sr * SP + sc + 8) = x1;
    };

    f32x4 acc[2][2] = {};
    gload(0);
    for (int kk = 0; kk < DD; kk += 64) {
        wstage();
        if (kk + 64 < DD) gload(kk + 64);
        sync_lds();
        #pragma unroll
        for (int k2 = 0; k2 < 2; k2++) {
            int ko = k2 * 32 + aq * 8;
            bf16x8 a0h = *(const bf16x8*)(ah + (R0 + am) * SP + ko);
            bf16x8 a1h = *(const bf16x8*)(ah + (R0 + 16 + am) * SP + ko);
            bf16x8 a0l = *(const bf16x8*)(al + (R0 + am) * SP + ko);
            bf16x8 a1l = *(const bf16x8*)(al + (R0 + 16 + am) * SP + ko);
            bf16x8 b0h = *(const bf16x8*)(bh + (F0 + am) * SP + ko);
            bf16x8 b1h = *(const bf16x8*)(bh + (F0 + 16 + am) * SP + ko);
            bf16x8 b0l = *(const bf16x8*)(bl + (F0 + am) * SP + ko);
            bf16x8 b1l = *(const bf16x8*)(bl + (F0 + 16 + am) * SP + ko);
            acc[0][0] = __builtin_amdgcn_mfma_f32_16x16x32_bf16(a0h, b0h, acc[0][0], 0, 0, 0);
            acc[0][1] = __builtin_amdgcn_mfma_f32_16x16x32_bf16(a0h, b1h, acc[0][1], 0, 0, 0);
            acc[1][0] = __builtin_amdgcn_mfma_f32_16x16x32_bf16(a1h, b0h, acc[1][0], 0, 0, 0);
            acc[1][1] = __builtin_amdgcn_mfma_f32_16x16x32_bf16(a1h, b1h, acc[1][1], 0, 0, 0);
            acc[0][0] = __builtin_amdgcn_mfma_f32_16x16x32_bf16(a0h, b0l, acc[0][0], 0, 0, 0);
            acc[0][1] = __builtin_amdgcn_mfma_f32_16x16x32_bf16(a0h, b1l, acc[0][1], 0, 0, 0);
            acc[1][0] = __builtin_amdgcn_mfma_f32_16x16x32_bf16(a1h, b0l, acc[1][0], 0, 0, 0);
            acc[1][1] = __builtin_amdgcn_mfma_f32_16x16x32_bf16(a1h, b1l, acc[1][1], 0, 0, 0);
            acc[0][0] = __builtin_amdgcn_mfma_f32_16x16x32_bf16(a0l, b0h, acc[0][0], 0, 0, 0);
            acc[0][1] = __builtin_amdgcn_mfma_f32_16x16x32_bf16(a0l, b1h, acc[0][1], 0, 0, 0);
            acc[1][0] = __builtin_amdgcn_mfma_f32_16x16x32_bf16(a1l, b0h, acc[1][0], 0, 0, 0);
            acc[1][1] = __builtin_amdgcn_mfma_f32_16x16x32_bf16(a1l, b1h, acc[1][1], 0, 0, 0);
        }
        sync_lds();
    }

    unsigned* tt = (unsigned*)smem;
    float* rs = (float*)(smem + 17408);
    float* rd = rs + 256;
    float* ash = rd + 256;
    if (t < 128) ash[t] = a[h * 2 * FF + t];
    int col = lane & 15, rbase = (lane >> 4) * 4;
    #pragma unroll
    for (int m16 = 0; m16 < 2; m16++) {
        #pragma unroll
        for (int n16 = 0; n16 < 2; n16++) {
            #pragma unroll
            for (int r = 0; r < 4; r++) {
                int nl = R0 + m16 * 16 + rbase + r;
                int f = F0 + n16 * 16 + col;
                float v = acc[m16][n16][r];
                unsigned short hi = f2bf(v);
                unsigned short lo = f2bf(v - bf2f(hi));
                tt[f * 68 + nl] = (unsigned)hi | ((unsigned)lo << 16);
            }
        }
    }
    __syncthreads();
    {
        int f = t >> 2, c = (t & 3) * 16;
        union { unsigned short s[16]; uint4 v[2]; } hb;
        float csum = 0.f;
        #pragma unroll
        for (int q = 0; q < 16; q++) {
            unsigned u = tt[f * 68 + c + q];
            hb.s[q] = (unsigned short)(u & 0xffffu);
            csum += bf2f((unsigned short)(u & 0xffffu)) + bf2f((unsigned short)(u >> 16));
        }
        uint4* dh = (uint4*)(hpT_hi + ((size_t)h * FF + f) * NN + n0 + c);
        dh[0] = hb.v[0]; dh[1] = hb.v[1];
        csum += __shfl_xor(csum, 1);
        csum += __shfl_xor(csum, 2);
        if ((t & 3) == 0) unsafeAtomicAdd(hpsum + h * FF + f, csum);
    }
    {
        int n = t & 63, g = t >> 6;
        float fsp = 0.f, fdp = 0.f;
        #pragma unroll
        for (int q = 0; q < 16; q++) {
            int f = g * 16 + q;
            unsigned u = tt[f * 68 + n];
            float v = bf2f((unsigned short)(u & 0xffffu)) + bf2f((unsigned short)(u >> 16));
            fsp += v * ash[f];
            fdp += v * ash[64 + f];
        }
        rs[g * 64 + n] = fsp;
        rd[g * 64 + n] = fdp;
    }
    __syncthreads();
    if (t < 64) {
        float fdv = rd[t] + rd[64 + t] + rd[128 + t] + rd[192 + t];
        fs[(size_t)h * NN + n0 + t] = rs[t] + rs[64 + t] + rs[128 + t] + rs[192 + t];
        fd[(size_t)h * NN + n0 + t] = fdv;
        unsigned key = fkey(fdv);
        #pragma unroll
        for (int off = 32; off; off >>= 1) key = max(key, (unsigned)__shfl_xor((int)key, off));
        if (t == 0) atomicMax(mxkey + h, key);
    }
}

// ================= Kernel 3: attention — hybrid: LDS-staged B, in-register A ============
// grid (NN/64, HH), block 256 = 4 waves x 16 q-rows. hbh (B operand) double-buffered in
// LDS via the r11 3-stage vmcnt pipeline; weights (A operand) generated in-register per
// lane (r13 scheme) from fd/adj regs loaded 2 tiles ahead (two alternating reg sets).
// One sync_lds per 64-j iteration. Fused normalize+ELU epilogue via ones-MFMA row sums.
__global__ __launch_bounds__(256) void k_attn(const float* __restrict__ fs,
                                              const float* __restrict__ fd,
                                              const unsigned* __restrict__ mxkey,
                                              const unsigned* __restrict__ adjw,
                                              const unsigned short* __restrict__ hpT_hi,
                                              const float* __restrict__ hpsum,
                                              float* __restrict__ outp) {
    __shared__ unsigned short hbh[2][64 * SP];   // 18432 B

    int t = threadIdx.x;
    int h = blockIdx.y;
    int wv = t >> 6;
    int q0 = blockIdx.x * 64 + wv * 16;   // wave's 16 q-rows
    int lane = t & 63;
    int am = lane & 15, aq = lane >> 4;
    int sr = t >> 2, sc = (t & 3) * 16;   // hbh staging map (f, j-chunk)

    const float LOG2E = 1.44269504f;
    float mfd = funkey(mxkey[h]);
    float fsr = fs[(size_t)h * NN + q0 + am];
    float sM = fsr + mfd;
    float mr = fmaxf(sM, LRELU_ALPHA * sM) * LOG2E;
    float Ac = __builtin_fmaf(fsr, LOG2E, -mr);
    float Bc = __builtin_fmaf(fsr, LRELU_ALPHA * LOG2E, -mr);

    const unsigned short* gH = hpT_hi + ((size_t)h * FF + sr) * NN + sc;
    const float* pfd = fd + (size_t)h * NN + aq * 8;
    const unsigned* prow = adjw + (size_t)(q0 + am) * (NN / 32);
    int bsh = aq * 8;

    f32x4 acc[4] = {};
    f32x4 accl = {};
    bf16x8 bones;
    #pragma unroll
    for (int i = 0; i < 8; i++) bones[i] = (short)0x3f80;   // bf16 1.0

    // pipeline registers: H tile (single set), F/adj (two alternating sets)
    uint4 H0, H1;
    float4 Fa0[2], Fa1[2], Fb0[2], Fb1[2];
    uint2 Aw[2];
    auto gloadH = [&](int j0) {
        H0 = *(const uint4*)(gH + j0);
        H1 = *(const uint4*)(gH + j0 + 8);
    };
    auto gloadF = [&](int j0, int s) {
        Fa0[s] = *(const float4*)(pfd + j0);
        Fa1[s] = *(const float4*)(pfd + j0 + 4);
        Fb0[s] = *(const float4*)(pfd + j0 + 32);
        Fb1[s] = *(const float4*)(pfd + j0 + 36);
        Aw[s]  = *(const uint2*)(prow + (j0 >> 5));
    };
    auto wstageH = [&](int buf) {
        *(uint4*)(&hbh[buf][sr * SP + sc]) = H0;
        *(uint4*)(&hbh[buf][sr * SP + sc + 8]) = H1;
    };
    auto agen = [&](float4 f0, float4 f1, unsigned word) -> bf16x8 {
        unsigned bits = word >> bsh;
        unsigned eu[8];
        #pragma unroll
        for (int q = 0; q < 2; q++) {
            float4 fdv = q ? f1 : f0;
            #pragma unroll
            for (int b = 0; b < 4; b++) {
                float fdL = f4c(fdv, b) * LOG2E;
                float t1 = Ac + fdL;
                float t2 = __builtin_fmaf(fdL, LRELU_ALPHA, Bc);
                float e = __builtin_amdgcn_exp2f(fmaxf(t1, t2));
                e = ((bits >> (q * 4 + b)) & 1u) ? e : 0.f;
                eu[q * 4 + b] = __float_as_uint(e);
            }
        }
        union { unsigned u[4]; bf16x8 v; } af;
        af.u[0] = __builtin_amdgcn_perm(eu[1], eu[0], 0x07060302);
        af.u[1] = __builtin_amdgcn_perm(eu[3], eu[2], 0x07060302);
        af.u[2] = __builtin_amdgcn_perm(eu[5], eu[4], 0x07060302);
        af.u[3] = __builtin_amdgcn_perm(eu[7], eu[6], 0x07060302);
        return af.v;
    };

    gloadH(0); gloadF(0, 0);
    wstageH(0);                 // waits vmcnt for tile 0 H only
    gloadH(64); gloadF(64, 1);  // tile 1 in flight
    sync_lds();
    const int NIT = NN / 64;
    for (int k = 0; k < NIT; k++) {
        int cur = k & 1;
        // A operands for tile k (regs loaded 2 iters ago, set cur)
        bf16x8 afA = agen(Fa0[cur], Fa1[cur], Aw[cur].x);   // k2=0
        bf16x8 afB = agen(Fb0[cur], Fb1[cur], Aw[cur].y);   // k2=1
        {
            int ko = aq * 8;
            bf16x8 b0 = *(const bf16x8*)(&hbh[cur][(am) * SP + ko]);
            bf16x8 b1 = *(const bf16x8*)(&hbh[cur][(16 + am) * SP + ko]);
            bf16x8 b2 = *(const bf16x8*)(&hbh[cur][(32 + am) * SP + ko]);
            bf16x8 b3 = *(const bf16x8*)(&hbh[cur][(48 + am) * SP + ko]);
            acc[0] = __builtin_amdgcn_mfma_f32_16x16x32_bf16(afA, b0, acc[0], 0, 0, 0);
            acc[1] = __builtin_amdgcn_mfma_f32_16x16x32_bf16(afA, b1, acc[1], 0, 0, 0);
            acc[2] = __builtin_amdgcn_mfma_f32_16x16x32_bf16(afA, b2, acc[2], 0, 0, 0);
            acc[3] = __builtin_amdgcn_mfma_f32_16x16x32_bf16(afA, b3, acc[3], 0, 0, 0);
            accl   = __builtin_amdgcn_mfma_f32_16x16x32_bf16(afA, bones, accl, 0, 0, 0);
        }
        {
            int ko = 32 + aq * 8;
            bf16x8 b0 = *(const bf16x8*)(&hbh[cur][(am) * SP + ko]);
            bf16x8 b1 = *(const bf16x8*)(&hbh[cur][(16 + am) * SP + ko]);
            bf16x8 b2 = *(const bf16x8*)(&hbh[cur][(32 + am) * SP + ko]);
            bf16x8 b3 = *(const bf16x8*)(&hbh[cur][(48 + am) * SP + ko]);
            acc[0] = __builtin_amdgcn_mfma_f32_16x16x32_bf16(afB, b0, acc[0], 0, 0, 0);
            acc[1] = __builtin_amdgcn_mfma_f32_16x16x32_bf16(afB, b1, acc[1], 0, 0, 0);
            acc[2] = __builtin_amdgcn_mfma_f32_16x16x32_bf16(afB, b2, acc[2], 0, 0, 0);
            acc[3] = __builtin_amdgcn_mfma_f32_16x16x32_bf16(afB, b3, acc[3], 0, 0, 0);
            accl   = __builtin_amdgcn_mfma_f32_16x16x32_bf16(afB, bones, accl, 0, 0, 0);
        }
        if (k < NIT - 1) {
            wstageH(cur ^ 1);                                   // tile k+1 (regs from k-1)
            if (k < NIT - 2) { gloadH((k + 2) * 64); gloadF((k + 2) * 64, cur); }
        }
        sync_lds();
    }

    // Fused epilogue: accl[r] is the row-sum for the same C/D row as acc[*][r].
    const float invN = 1.0f / NN;
    int col = lane & 15, rbase = (lane >> 4) * 4;
    #pragma unroll
    for (int r = 0; r < 4; r++) {
        int row = q0 + rbase + r;
        float l = accl[r];
        float rl = 1.f / l;
        #pragma unroll
        for (int Fi = 0; Fi < 4; Fi++) {
            int f = Fi * 16 + col;
            float v;
            if (l > 0.f) v = acc[Fi][r] * rl;
            else         v = hpsum[h * FF + f] * invN;   // all-masked row fallback
            v = v > 0.f ? v : __expf(v) - 1.f;
            outp[(size_t)row * (HH * FF) + h * FF + f] = v;
        }
    }
}

extern "C" void kernel_launch(void* const* d_in, const int* in_sizes, int n_in,
                              void* d_out, int out_size, void* d_ws, size_t ws_size,
                              hipStream_t stream) {
    const float* hmat = (const float*)d_in[0];
    const int*   adj  = (const int*)d_in[1];
    const float* W    = (const float*)d_in[2];
    const float* a    = (const float*)d_in[3];
    float* out = (float*)d_out;

    char* ws = (char*)d_ws;
    unsigned short* hpT_hi = (unsigned short*)(ws);                 // 4 MB
    unsigned*       adjw   = (unsigned*)(ws + (4u << 20));          // 2 MB
    unsigned short* wt_hi  = (unsigned short*)(ws + (6u << 20));    // 512 KB
    unsigned short* wt_lo  = (unsigned short*)(ws + (6u << 20) + (512u << 10));
    float* fs    = (float*)(ws + (7u << 20));                       // 128 KB
    float* fd    = (float*)(ws + (7u << 20) + (128u << 10));        // 128 KB
    unsigned* mxkey = (unsigned*)(ws + (7u << 20) + (256u << 10));  // 64 B
    float* hpsum = (float*)(mxkey + 16);                            // 2 KB

    k_prep   <<<dim3(4161),          256, 0, stream>>>(adj, W, adjw, wt_hi, wt_lo,
                                                       mxkey, hpsum);
    k_hp_mfma<<<dim3(64, 8),         256, 0, stream>>>(hmat, wt_hi, wt_lo, a,
                                                       hpT_hi, fs, fd, hpsum, mxkey);
    k_attn   <<<dim3(NN / 64, HH),   256, 0, stream>>>(fs, fd, mxkey, adjw,
                                                       hpT_hi, hpsum, out);
}

// Round 16
// 190.396 us; speedup vs baseline: 1.6477x; 1.6477x over previous
//
#include <hip/hip_runtime.h>

#define NN 4096
#define DD 512
#define HH 8
#define FF 64
#define LRELU_ALPHA 0.2f
#define SP 72   // LDS row stride in bf16 elems

typedef __attribute__((ext_vector_type(8))) short bf16x8;
typedef __attribute__((ext_vector_type(4))) float f32x4;

__device__ __forceinline__ float f4c(const float4& v, int k) {
    return k == 0 ? v.x : (k == 1 ? v.y : (k == 2 ? v.z : v.w));
}
__device__ __forceinline__ void f4s(float4& v, int k, float x) {
    if (k == 0) v.x = x; else if (k == 1) v.y = x; else if (k == 2) v.z = x; else v.w = x;
}
__device__ __forceinline__ unsigned short f2bf(float x) {   // RNE float->bf16
    unsigned u = __float_as_uint(x);
    return (unsigned short)((u + 0x7fffu + ((u >> 16) & 1u)) >> 16);
}
__device__ __forceinline__ float bf2f(unsigned short h) {
    return __uint_as_float(((unsigned)h) << 16);
}
// monotone float<->uint key for atomicMax on arbitrary-sign floats
__device__ __forceinline__ unsigned fkey(float x) {
    unsigned u = __float_as_uint(x);
    return (u & 0x80000000u) ? ~u : (u | 0x80000000u);
}
__device__ __forceinline__ float funkey(unsigned k) {
    unsigned u = (k & 0x80000000u) ? (k ^ 0x80000000u) : ~k;
    return __uint_as_float(u);
}
// CK-style barrier: drain LDS counts only; in-flight global->register loads survive.
__device__ __forceinline__ void sync_lds() {
    asm volatile("s_waitcnt lgkmcnt(0)\n\ts_barrier" ::: "memory");
}

// ================= Kernel 1: fused prep =================
__global__ __launch_bounds__(256) void k_prep(const int* __restrict__ adj,
                                              const float* __restrict__ W,
                                              unsigned* __restrict__ adjw,
                                              unsigned short* __restrict__ wt_hi,
                                              unsigned short* __restrict__ wt_lo,
                                              unsigned* __restrict__ mxkey,
                                              float* __restrict__ hpsum) {
    __shared__ float tile[64][65];
    int b = blockIdx.x, t = threadIdx.x;
    if (b < 4096) {
        int lane = t & 63;
        #pragma unroll
        for (int i = 0; i < 16; i++) {
            int tid = ((b * 16 + i) << 8) + t;
            unsigned long long mask = __ballot(adj[tid] > 0);
            if (lane == 0) {
                int base = tid >> 5;
                adjw[base] = (unsigned)mask;
                adjw[base + 1] = (unsigned)(mask >> 32);
            }
        }
    } else if (b < 4160) {
        int idx = b - 4096;
        int h = idx >> 3;
        int d0 = (idx & 7) * 64;
        #pragma unroll
        for (int kidx = 0; kidx < 4; kidx++) {
            int id = t + 256 * kidx;
            int dd = id >> 4, f4i = (id & 15) * 4;
            float4 v = *(const float4*)(W + ((size_t)(h * DD + d0 + dd)) * FF + f4i);
            tile[dd][f4i] = v.x; tile[dd][f4i + 1] = v.y;
            tile[dd][f4i + 2] = v.z; tile[dd][f4i + 3] = v.w;
        }
        __syncthreads();
        int f = t >> 2, c = (t & 3) * 16;
        union { unsigned short s[16]; uint4 v[2]; } hb, lb;
        #pragma unroll
        for (int q = 0; q < 16; q++) {
            float v = tile[c + q][f];
            unsigned short hi = f2bf(v);
            hb.s[q] = hi;
            lb.s[q] = f2bf(v - bf2f(hi));
        }
        uint4* dh = (uint4*)(wt_hi + ((size_t)h * FF + f) * DD + d0 + c);
        uint4* dl = (uint4*)(wt_lo + ((size_t)h * FF + f) * DD + d0 + c);
        dh[0] = hb.v[0]; dh[1] = hb.v[1];
        dl[0] = lb.v[0]; dl[1] = lb.v[1];
    } else {
        if (t < 16) mxkey[t] = 0u;
        hpsum[t] = 0.f;
        hpsum[t + 256] = 0.f;
    }
}

// ================= Kernel 2: hp GEMM, 3-stage pipelined K-loop ========
__global__ __launch_bounds__(256) void k_hp_mfma(const float* __restrict__ hmat,
                                                 const unsigned short* __restrict__ whi,
                                                 const unsigned short* __restrict__ wlo,
                                                 const float* __restrict__ a,
                                                 unsigned short* __restrict__ hpT_hi,
                                                 float* __restrict__ fs,
                                                 float* __restrict__ fd,
                                                 float* __restrict__ hpsum,
                                                 unsigned* __restrict__ mxkey) {
    __shared__ char smem[4 * 64 * SP * 2];   // 36864 B
    unsigned short* ah = (unsigned short*)smem;
    unsigned short* al = ah + 64 * SP;
    unsigned short* bh = al + 64 * SP;
    unsigned short* bl = bh + 64 * SP;

    int t = threadIdx.x;
    int h = blockIdx.y;
    int n0 = blockIdx.x * 64;
    int lane = t & 63;
    int w = t >> 6;
    int R0 = (w >> 1) * 32, F0 = (w & 1) * 32;
    int am = lane & 15, aq = lane >> 4;
    int sr = t >> 2, sc = (t & 3) * 16;

    const float* gha = hmat + (size_t)(n0 + sr) * DD;
    const unsigned short* gbh = whi + ((size_t)h * FF + sr) * DD;
    const unsigned short* gbl = wlo + ((size_t)h * FF + sr) * DD;

    float4 p0, p1, p2, p3;
    uint4 w0, w1, x0, x1;
    auto gload = [&](int kk) {
        p0 = *(const float4*)(gha + kk + sc);
        p1 = *(const float4*)(gha + kk + sc + 4);
        p2 = *(const float4*)(gha + kk + sc + 8);
        p3 = *(const float4*)(gha + kk + sc + 12);
        const uint4* s2 = (const uint4*)(gbh + kk + sc);
        const uint4* s3 = (const uint4*)(gbl + kk + sc);
        w0 = s2[0]; w1 = s2[1]; x0 = s3[0]; x1 = s3[1];
    };
    auto wstage = [&]() {
        union { unsigned short s[16]; uint4 v[2]; } hb, lb;
        #pragma unroll
        for (int q = 0; q < 16; q++) {
            float v = q < 4 ? f4c(p0, q) : q < 8 ? f4c(p1, q - 4)
                      : q < 12 ? f4c(p2, q - 8) : f4c(p3, q - 12);
            unsigned short hi = f2bf(v);
            hb.s[q] = hi;
            lb.s[q] = f2bf(v - bf2f(hi));
        }
        *(uint4*)(ah + sr * SP + sc) = hb.v[0]; *(uint4*)(ah + sr * SP + sc + 8) = hb.v[1];
        *(uint4*)(al + sr * SP + sc) = lb.v[0]; *(uint4*)(al + sr * SP + sc + 8) = lb.v[1];
        *(uint4*)(bh + sr * SP + sc) = w0; *(uint4*)(bh + sr * SP + sc + 8) = w1;
        *(uint4*)(bl + sr * SP + sc) = x0; *(uint4*)(bl + sr * SP + sc + 8) = x1;
    };

    f32x4 acc[2][2] = {};
    gload(0);
    for (int kk = 0; kk < DD; kk += 64) {
        wstage();
        if (kk + 64 < DD) gload(kk + 64);
        sync_lds();
        #pragma unroll
        for (int k2 = 0; k2 < 2; k2++) {
            int ko = k2 * 32 + aq * 8;
            bf16x8 a0h = *(const bf16x8*)(ah + (R0 + am) * SP + ko);
            bf16x8 a1h = *(const bf16x8*)(ah + (R0 + 16 + am) * SP + ko);
            bf16x8 a0l = *(const bf16x8*)(al + (R0 + am) * SP + ko);
            bf16x8 a1l = *(const bf16x8*)(al + (R0 + 16 + am) * SP + ko);
            bf16x8 b0h = *(const bf16x8*)(bh + (F0 + am) * SP + ko);
            bf16x8 b1h = *(const bf16x8*)(bh + (F0 + 16 + am) * SP + ko);
            bf16x8 b0l = *(const bf16x8*)(bl + (F0 + am) * SP + ko);
            bf16x8 b1l = *(const bf16x8*)(bl + (F0 + 16 + am) * SP + ko);
            acc[0][0] = __builtin_amdgcn_mfma_f32_16x16x32_bf16(a0h, b0h, acc[0][0], 0, 0, 0);
            acc[0][1] = __builtin_amdgcn_mfma_f32_16x16x32_bf16(a0h, b1h, acc[0][1], 0, 0, 0);
            acc[1][0] = __builtin_amdgcn_mfma_f32_16x16x32_bf16(a1h, b0h, acc[1][0], 0, 0, 0);
            acc[1][1] = __builtin_amdgcn_mfma_f32_16x16x32_bf16(a1h, b1h, acc[1][1], 0, 0, 0);
            acc[0][0] = __builtin_amdgcn_mfma_f32_16x16x32_bf16(a0h, b0l, acc[0][0], 0, 0, 0);
            acc[0][1] = __builtin_amdgcn_mfma_f32_16x16x32_bf16(a0h, b1l, acc[0][1], 0, 0, 0);
            acc[1][0] = __builtin_amdgcn_mfma_f32_16x16x32_bf16(a1h, b0l, acc[1][0], 0, 0, 0);
            acc[1][1] = __builtin_amdgcn_mfma_f32_16x16x32_bf16(a1h, b1l, acc[1][1], 0, 0, 0);
            acc[0][0] = __builtin_amdgcn_mfma_f32_16x16x32_bf16(a0l, b0h, acc[0][0], 0, 0, 0);
            acc[0][1] = __builtin_amdgcn_mfma_f32_16x16x32_bf16(a0l, b1h, acc[0][1], 0, 0, 0);
            acc[1][0] = __builtin_amdgcn_mfma_f32_16x16x32_bf16(a1l, b0h, acc[1][0], 0, 0, 0);
            acc[1][1] = __builtin_amdgcn_mfma_f32_16x16x32_bf16(a1l, b1h, acc[1][1], 0, 0, 0);
        }
        sync_lds();
    }

    unsigned* tt = (unsigned*)smem;
    float* rs = (float*)(smem + 17408);
    float* rd = rs + 256;
    float* ash = rd + 256;
    if (t < 128) ash[t] = a[h * 2 * FF + t];
    int col = lane & 15, rbase = (lane >> 4) * 4;
    #pragma unroll
    for (int m16 = 0; m16 < 2; m16++) {
        #pragma unroll
        for (int n16 = 0; n16 < 2; n16++) {
            #pragma unroll
            for (int r = 0; r < 4; r++) {
                int nl = R0 + m16 * 16 + rbase + r;
                int f = F0 + n16 * 16 + col;
                float v = acc[m16][n16][r];
                unsigned short hi = f2bf(v);
                unsigned short lo = f2bf(v - bf2f(hi));
                tt[f * 68 + nl] = (unsigned)hi | ((unsigned)lo << 16);
            }
        }
    }
    __syncthreads();
    {
        int f = t >> 2, c = (t & 3) * 16;
        union { unsigned short s[16]; uint4 v[2]; } hb;
        float csum = 0.f;
        #pragma unroll
        for (int q = 0; q < 16; q++) {
            unsigned u = tt[f * 68 + c + q];
            hb.s[q] = (unsigned short)(u & 0xffffu);
            csum += bf2f((unsigned short)(u & 0xffffu)) + bf2f((unsigned short)(u >> 16));
        }
        uint4* dh = (uint4*)(hpT_hi + ((size_t)h * FF + f) * NN + n0 + c);
        dh[0] = hb.v[0]; dh[1] = hb.v[1];
        csum += __shfl_xor(csum, 1);
        csum += __shfl_xor(csum, 2);
        if ((t & 3) == 0) unsafeAtomicAdd(hpsum + h * FF + f, csum);
    }
    {
        int n = t & 63, g = t >> 6;
        float fsp = 0.f, fdp = 0.f;
        #pragma unroll
        for (int q = 0; q < 16; q++) {
            int f = g * 16 + q;
            unsigned u = tt[f * 68 + n];
            float v = bf2f((unsigned short)(u & 0xffffu)) + bf2f((unsigned short)(u >> 16));
            fsp += v * ash[f];
            fdp += v * ash[64 + f];
        }
        rs[g * 64 + n] = fsp;
        rd[g * 64 + n] = fdp;
    }
    __syncthreads();
    if (t < 64) {
        float fdv = rd[t] + rd[64 + t] + rd[128 + t] + rd[192 + t];
        fs[(size_t)h * NN + n0 + t] = rs[t] + rs[64 + t] + rs[128 + t] + rs[192 + t];
        fd[(size_t)h * NN + n0 + t] = fdv;
        unsigned key = fkey(fdv);
        #pragma unroll
        for (int off = 32; off; off >>= 1) key = max(key, (unsigned)__shfl_xor((int)key, off));
        if (t == 0) atomicMax(mxkey + h, key);
    }
}

// ================= Kernel 3: attention — hybrid, spill-free (unrolled x2) ============
// grid (NN/64, HH), block 256 = 4 waves x 16 q-rows. B (hbh) double-buffered in LDS via
// the r11 vmcnt pipeline; A (weights) generated in-register from NAMED X/Y reg sets
// (X = even tiles, Y = odd) — no runtime-indexed private arrays, so no scratch spill.
__global__ __launch_bounds__(256) void k_attn(const float* __restrict__ fs,
                                              const float* __restrict__ fd,
                                              const unsigned* __restrict__ mxkey,
                                              const unsigned* __restrict__ adjw,
                                              const unsigned short* __restrict__ hpT_hi,
                                              const float* __restrict__ hpsum,
                                              float* __restrict__ outp) {
    __shared__ unsigned short hbh[2][64 * SP];   // 18432 B

    int t = threadIdx.x;
    int h = blockIdx.y;
    int wv = t >> 6;
    int q0 = blockIdx.x * 64 + wv * 16;   // wave's 16 q-rows
    int lane = t & 63;
    int am = lane & 15, aq = lane >> 4;
    int sr = t >> 2, sc = (t & 3) * 16;   // hbh staging map (f, j-chunk)

    const float LOG2E = 1.44269504f;
    float mfd = funkey(mxkey[h]);
    float fsr = fs[(size_t)h * NN + q0 + am];
    float sM = fsr + mfd;
    float mr = fmaxf(sM, LRELU_ALPHA * sM) * LOG2E;
    float Ac = __builtin_fmaf(fsr, LOG2E, -mr);
    float Bc = __builtin_fmaf(fsr, LRELU_ALPHA * LOG2E, -mr);

    const unsigned short* gH = hpT_hi + ((size_t)h * FF + sr) * NN + sc;
    const float* pfd = fd + (size_t)h * NN + aq * 8;
    const unsigned* prow = adjw + (size_t)(q0 + am) * (NN / 32);
    int bsh = aq * 8;

    f32x4 acc[4] = {};
    f32x4 accl = {};
    bf16x8 bones;
    #pragma unroll
    for (int i = 0; i < 8; i++) bones[i] = (short)0x3f80;   // bf16 1.0

    // pipeline registers — all NAMED (no runtime-indexed arrays -> no scratch)
    uint4 H0, H1;                                   // H tile (single set)
    float4 XFa0, XFa1, XFb0, XFb1; uint2 XAw;       // F/adj for even tiles
    float4 YFa0, YFa1, YFb0, YFb1; uint2 YAw;       // F/adj for odd tiles

    auto gloadH = [&](int j0) {
        H0 = *(const uint4*)(gH + j0);
        H1 = *(const uint4*)(gH + j0 + 8);
    };
    auto gloadFX = [&](int j0) {
        XFa0 = *(const float4*)(pfd + j0);
        XFa1 = *(const float4*)(pfd + j0 + 4);
        XFb0 = *(const float4*)(pfd + j0 + 32);
        XFb1 = *(const float4*)(pfd + j0 + 36);
        XAw  = *(const uint2*)(prow + (j0 >> 5));
    };
    auto gloadFY = [&](int j0) {
        YFa0 = *(const float4*)(pfd + j0);
        YFa1 = *(const float4*)(pfd + j0 + 4);
        YFb0 = *(const float4*)(pfd + j0 + 32);
        YFb1 = *(const float4*)(pfd + j0 + 36);
        YAw  = *(const uint2*)(prow + (j0 >> 5));
    };
    auto wstageH = [&](int buf) {
        *(uint4*)(&hbh[buf][sr * SP + sc]) = H0;
        *(uint4*)(&hbh[buf][sr * SP + sc + 8]) = H1;
    };
    auto agen = [&](float4 f0, float4 f1, unsigned word) -> bf16x8 {
        unsigned bits = word >> bsh;
        unsigned eu[8];
        #pragma unroll
        for (int q = 0; q < 2; q++) {
            float4 fdv = q ? f1 : f0;
            #pragma unroll
            for (int b = 0; b < 4; b++) {
                float fdL = f4c(fdv, b) * LOG2E;
                float t1 = Ac + fdL;
                float t2 = __builtin_fmaf(fdL, LRELU_ALPHA, Bc);
                float e = __builtin_amdgcn_exp2f(fmaxf(t1, t2));
                e = ((bits >> (q * 4 + b)) & 1u) ? e : 0.f;
                eu[q * 4 + b] = __float_as_uint(e);
            }
        }
        union { unsigned u[4]; bf16x8 v; } af;
        af.u[0] = __builtin_amdgcn_perm(eu[1], eu[0], 0x07060302);
        af.u[1] = __builtin_amdgcn_perm(eu[3], eu[2], 0x07060302);
        af.u[2] = __builtin_amdgcn_perm(eu[5], eu[4], 0x07060302);
        af.u[3] = __builtin_amdgcn_perm(eu[7], eu[6], 0x07060302);
        return af.v;
    };
    auto mfma_tile = [&](int buf, bf16x8 afA, bf16x8 afB) {
        {
            int ko = aq * 8;
            bf16x8 b0 = *(const bf16x8*)(&hbh[buf][(am) * SP + ko]);
            bf16x8 b1 = *(const bf16x8*)(&hbh[buf][(16 + am) * SP + ko]);
            bf16x8 b2 = *(const bf16x8*)(&hbh[buf][(32 + am) * SP + ko]);
            bf16x8 b3 = *(const bf16x8*)(&hbh[buf][(48 + am) * SP + ko]);
            acc[0] = __builtin_amdgcn_mfma_f32_16x16x32_bf16(afA, b0, acc[0], 0, 0, 0);
            acc[1] = __builtin_amdgcn_mfma_f32_16x16x32_bf16(afA, b1, acc[1], 0, 0, 0);
            acc[2] = __builtin_amdgcn_mfma_f32_16x16x32_bf16(afA, b2, acc[2], 0, 0, 0);
            acc[3] = __builtin_amdgcn_mfma_f32_16x16x32_bf16(afA, b3, acc[3], 0, 0, 0);
            accl   = __builtin_amdgcn_mfma_f32_16x16x32_bf16(afA, bones, accl, 0, 0, 0);
        }
        {
            int ko = 32 + aq * 8;
            bf16x8 b0 = *(const bf16x8*)(&hbh[buf][(am) * SP + ko]);
            bf16x8 b1 = *(const bf16x8*)(&hbh[buf][(16 + am) * SP + ko]);
            bf16x8 b2 = *(const bf16x8*)(&hbh[buf][(32 + am) * SP + ko]);
            bf16x8 b3 = *(const bf16x8*)(&hbh[buf][(48 + am) * SP + ko]);
            acc[0] = __builtin_amdgcn_mfma_f32_16x16x32_bf16(afB, b0, acc[0], 0, 0, 0);
            acc[1] = __builtin_amdgcn_mfma_f32_16x16x32_bf16(afB, b1, acc[1], 0, 0, 0);
            acc[2] = __builtin_amdgcn_mfma_f32_16x16x32_bf16(afB, b2, acc[2], 0, 0, 0);
            acc[3] = __builtin_amdgcn_mfma_f32_16x16x32_bf16(afB, b3, acc[3], 0, 0, 0);
            accl   = __builtin_amdgcn_mfma_f32_16x16x32_bf16(afB, bones, accl, 0, 0, 0);
        }
    };

    const int NIT = NN / 64;   // 64, even
    gloadH(0); gloadFX(0);
    wstageH(0);                  // tile 0 -> buf0 (waits vmcnt for tile-0 H only)
    gloadH(64); gloadFY(64);     // tile 1 in flight
    sync_lds();
    for (int kk = 0; kk < NIT; kk += 2) {
        // even tile kk: buf0, X regs
        {
            bf16x8 afA = agen(XFa0, XFa1, XAw.x);
            bf16x8 afB = agen(XFb0, XFb1, XAw.y);
            mfma_tile(0, afA, afB);
            wstageH(1);                                     // tile kk+1 (H loaded last half)
            if (kk + 2 < NIT) { gloadH((kk + 2) * 64); gloadFX((kk + 2) * 64); }
            sync_lds();
        }
        // odd tile kk+1: buf1, Y regs
        {
            bf16x8 afA = agen(YFa0, YFa1, YAw.x);
            bf16x8 afB = agen(YFb0, YFb1, YAw.y);
            mfma_tile(1, afA, afB);
            if (kk + 2 < NIT) {
                wstageH(0);                                 // tile kk+2
                if (kk + 3 < NIT) { gloadH((kk + 3) * 64); gloadFY((kk + 3) * 64); }
            }
            sync_lds();
        }
    }

    // Fused epilogue: accl[r] is the row-sum for the same C/D row as acc[*][r].
    const float invN = 1.0f / NN;
    int col = lane & 15, rbase = (lane >> 4) * 4;
    #pragma unroll
    for (int r = 0; r < 4; r++) {
        int row = q0 + rbase + r;
        float l = accl[r];
        float rl = 1.f / l;
        #pragma unroll
        for (int Fi = 0; Fi < 4; Fi++) {
            int f = Fi * 16 + col;
            float v;
            if (l > 0.f) v = acc[Fi][r] * rl;
            else         v = hpsum[h * FF + f] * invN;   // all-masked row fallback
            v = v > 0.f ? v : __expf(v) - 1.f;
            outp[(size_t)row * (HH * FF) + h * FF + f] = v;
        }
    }
}

extern "C" void kernel_launch(void* const* d_in, const int* in_sizes, int n_in,
                              void* d_out, int out_size, void* d_ws, size_t ws_size,
                              hipStream_t stream) {
    const float* hmat = (const float*)d_in[0];
    const int*   adj  = (const int*)d_in[1];
    const float* W    = (const float*)d_in[2];
    const float* a    = (const float*)d_in[3];
    float* out = (float*)d_out;

    char* ws = (char*)d_ws;
    unsigned short* hpT_hi = (unsigned short*)(ws);                 // 4 MB
    unsigned*       adjw   = (unsigned*)(ws + (4u << 20));          // 2 MB
    unsigned short* wt_hi  = (unsigned short*)(ws + (6u << 20));    // 512 KB
    unsigned short* wt_lo  = (unsigned short*)(ws + (6u << 20) + (512u << 10));
    float* fs    = (float*)(ws + (7u << 20));                       // 128 KB
    float* fd    = (float*)(ws + (7u << 20) + (128u << 10));        // 128 KB
    unsigned* mxkey = (unsigned*)(ws + (7u << 20) + (256u << 10));  // 64 B
    float* hpsum = (float*)(mxkey + 16);                            // 2 KB

    k_prep   <<<dim3(4161),          256, 0, stream>>>(adj, W, adjw, wt_hi, wt_lo,
                                                       mxkey, hpsum);
    k_hp_mfma<<<dim3(64, 8),         256, 0, stream>>>(hmat, wt_hi, wt_lo, a,
                                                       hpT_hi, fs, fd, hpsum, mxkey);
    k_attn   <<<dim3(NN / 64, HH),   256, 0, stream>>>(fs, fd, mxkey, adjw,
                                                       hpT_hi, hpsum, out);
}